// Round 1
// baseline (284.275 us; speedup 1.0000x reference)
//
#include <hip/hip_runtime.h>
#include <cstdint>

#define A_NUM 9
#define C_NUM 20
#define B_SZ 32
#define HW 784            // 28*28
#define P_NUM (A_NUM*HW)  // 7056
#define NBOX 64
#define CIN 1280
#define HID 128
#define M_IDX 4096
#define KS_ALL 40         // 1280/32 k-steps, full K in one block
#define ASTR 40           // padded A LDS row stride in bf16 elems (80 B)
#define HSTR 136          // h LDS row stride in bf16 elems (272 B)
#define OSTR 80           // Hd row stride in floats (65 used, pad to 80)
#define IOU_PB 64         // p-rows per iou block

// output layout (flat concat in return order)
#define CONF_OFF 0
#define OFFS_OFF (2*M_IDX)                 // 8192
#define CLS_OFF  (OFFS_OFF + 4*M_IDX)      // 24576
#define IOU_OFF  (CLS_OFF + C_NUM*M_IDX)   // 106496

// fused-kernel grid split
#define GEMM_BLKS (13*B_SZ)                       // 416
#define IOU_BX ((P_NUM + IOU_PB - 1)/IOU_PB)      // 111
#define IOU_BLKS (IOU_BX*B_SZ)                    // 3552

typedef short bf16x8 __attribute__((ext_vector_type(8)));
typedef float f32x4  __attribute__((ext_vector_type(4)));

// round-half-up fp32->bf16, packed pair into one dword
__device__ __forceinline__ unsigned pack_bf16(float lo, float hi) {
  unsigned a = __builtin_bit_cast(unsigned, lo);
  unsigned b = __builtin_bit_cast(unsigned, hi);
  return ((a + 0x8000u) >> 16) | ((b + 0x8000u) & 0xffff0000u);
}

// ---- weight prep: W1 and W2 fp32 -> bf16 MFMA B-fragment order -------------
// W1f layout: [ks(40)][ntile(8)][lane(64)][k8], lane=(quad,lo): n=ntile*16+lo,
// k = ks*32 + quad*8 + j.
// W2f layout: [ks(4)][ntile(5)][lane(64)][k8], n(=o)=ntile*16+lo (o>=65 -> 0),
// k over HID=128.
__global__ __launch_bounds__(256) void prep_w(const float* __restrict__ W1,
                                              const float* __restrict__ W2,
                                              uint4* __restrict__ W1f,
                                              uint4* __restrict__ W2f) {
  int id = blockIdx.x * 256 + threadIdx.x;  // 85*256 = 21760 threads
  if (id < 20480) {
    int lane = id & 63;
    int ntile = (id >> 6) & 7;
    int ks = id >> 9;                       // 0..39
    int lo = lane & 15, quad = lane >> 4;
    int n = ntile * 16 + lo;
    int k0 = ks * 32 + quad * 8;
    const float* src = W1 + n * CIN + k0;
    float4 x = *(const float4*)src;
    float4 y = *(const float4*)(src + 4);
    uint4 p;
    p.x = pack_bf16(x.x, x.y);
    p.y = pack_bf16(x.z, x.w);
    p.z = pack_bf16(y.x, y.y);
    p.w = pack_bf16(y.z, y.w);
    W1f[id] = p;
  } else {
    int i2 = id - 20480;                    // 0..1279
    int lane = i2 & 63;
    int ntile = (i2 >> 6) % 5;
    int ks = i2 / 320;                      // 0..3
    int lo = lane & 15, quad = lane >> 4;
    int n = ntile * 16 + lo;
    int k0 = ks * 32 + quad * 8;
    uint4 p = (uint4){0, 0, 0, 0};
    if (n < 5 * A_NUM + C_NUM) {
      const float* src = W2 + n * HID + k0;
      float4 x = *(const float4*)src;
      float4 y = *(const float4*)(src + 4);
      p.x = pack_bf16(x.x, x.y);
      p.y = pack_bf16(x.z, x.w);
      p.z = pack_bf16(y.x, y.y);
      p.w = pack_bf16(y.z, y.w);
    }
    W2f[i2] = p;
  }
}

// ---- fused: layer-1 GEMM (full K) + layer-2 head epilogue + IoU ------------
union SharedU {
  struct { unsigned short Asm[2][64 * ASTR]; } g;   // 10240 B (main loop)
  struct { unsigned short hs[64 * HSTR]; } e;       // 17408 B (epilogue)
  struct { float sb[NBOX * 5]; float4 sp4[IOU_PB]; } i;  // 2304 B (iou)
};

__global__ __launch_bounds__(256) void fused_main(
    const float* __restrict__ F, const unsigned short* __restrict__ W1f,
    const unsigned short* __restrict__ W2f, const float* __restrict__ b1,
    const float* __restrict__ b2, float* __restrict__ Hd,
    const float* __restrict__ gridc, const float* __restrict__ anc,
    const float* __restrict__ bboxes, float* __restrict__ iou_out) {
  __shared__ SharedU sh;
  const int bid = blockIdx.x;
  const int t = threadIdx.x;

  if (bid >= GEMM_BLKS) {
    // ================= IoU part (unchanged math) =================
    const int bid2 = bid - GEMM_BLKS;
    const int b = bid2 / IOU_BX;
    const int p0 = (bid2 - b * IOU_BX) * IOU_PB;
    float* sb = sh.i.sb;
    float4* sp4 = sh.i.sp4;
    for (int i = t; i < NBOX * 5; i += 256) sb[i] = bboxes[b * NBOX * 5 + i];
    if (t < IOU_PB) {
      int p = p0 + t;
      float x1 = 0.f, y1 = 0.f, x2 = 0.f, y2 = 0.f;
      if (p < P_NUM) {
        int a = p / HW, hw = p - a * HW;
        float2 c = ((const float2*)gridc)[b * HW + hw];
        float hx = anc[a * 2 + 0] * 0.5f, hy = anc[a * 2 + 1] * 0.5f;
        x1 = c.x - hx; y1 = c.y - hy; x2 = c.x + hx; y2 = c.y + hy;
      }
      sp4[t] = make_float4(x1, y1, x2, y2);
    }
    __syncthreads();
    const int nl = (t & 15) * 4;
    const int pi = t >> 4;
#pragma unroll
    for (int ip = 0; ip < 4; ip++) {
      const int pl = pi + 16 * ip;
      const int p = p0 + pl;
      const float4 pb = sp4[pl];
      const float spA = (pb.z - pb.x) * (pb.w - pb.y);
      float4 res;
#pragma unroll
      for (int jn = 0; jn < 4; jn++) {
        const int n = nl + jn;
        float bx1 = sb[n * 5 + 0], by1 = sb[n * 5 + 1];
        float bx2 = sb[n * 5 + 2], by2 = sb[n * 5 + 3];
        float s_b = (bx2 - bx1) * (by2 - by1);
        float ix1 = fmaxf(pb.x, bx1), iy1 = fmaxf(pb.y, by1);
        float ix2 = fminf(pb.z, bx2), iy2 = fminf(pb.w, by2);
        float si = fmaxf(ix2 - ix1, 0.f) * fmaxf(iy2 - iy1, 0.f);
        float su = spA + s_b - si;
        float iou = fmaxf(si / (su + 1e-8f), 0.f);
        bool invalid = (su <= 0.f) | (spA <= 0.f) | (s_b <= 0.f) | (bx1 < 0.f);
        float v = invalid ? 0.f : iou;
        if (jn == 0) res.x = v; else if (jn == 1) res.y = v;
        else if (jn == 2) res.z = v; else res.w = v;
      }
      if (p < P_NUM)
        *(float4*)&iou_out[((size_t)(b * P_NUM + p)) * 64 + nl] = res;
    }
    return;
  }

  // ================= GEMM part: 64m x 128n, K=1280 =================
  const int b = bid / 13;
  const int m0 = (bid - b * 13) * 64;
  const int wave = t >> 6, lane = t & 63;
  const int quad = lane >> 4, lo = lane & 15;

  const int sm = t & 63;
  const int kh = t >> 6;
  const int gm = m0 + sm;
  const bool mval = gm < HW;
  const float* Fb = F + (size_t)b * CIN * HW + (mval ? gm : 0);

  f32x4 acc[4][2];
#pragma unroll
  for (int i = 0; i < 4; i++)
#pragma unroll
    for (int j = 0; j < 2; j++) acc[i][j] = (f32x4){0.f, 0.f, 0.f, 0.f};

  float va[8];
  uint4 vb[2][2];  // [buf][j]

  auto loadA = [&](int kk) {
    const int k0 = kk * 32 + kh * 8;
#pragma unroll
    for (int i = 0; i < 8; i++) va[i] = Fb[(size_t)(k0 + i) * HW];
  };
  auto loadB = [&](int kk, uint4* dst) {
    const unsigned short* g =
        W1f + (size_t)((kk * 8 + wave * 2) * 64 + lane) * 8;
    dst[0] = *(const uint4*)g;
    dst[1] = *(const uint4*)(g + 512);  // next ntile
  };
  auto stageA = [&](int buf) {
    uint4 p;
    if (mval) {
      p.x = pack_bf16(va[0], va[1]);
      p.y = pack_bf16(va[2], va[3]);
      p.z = pack_bf16(va[4], va[5]);
      p.w = pack_bf16(va[6], va[7]);
    } else {
      p = (uint4){0, 0, 0, 0};
    }
    *(uint4*)&sh.g.Asm[buf][sm * ASTR + kh * 8] = p;
  };
  auto compute = [&](int buf, uint4* bv) {
    const unsigned short* Ab = &sh.g.Asm[buf][lo * ASTR + quad * 8];
    bf16x8 af[4];
#pragma unroll
    for (int i = 0; i < 4; i++) af[i] = *(const bf16x8*)(Ab + i * 16 * ASTR);
    bf16x8 b0 = __builtin_bit_cast(bf16x8, bv[0]);
    bf16x8 b1v = __builtin_bit_cast(bf16x8, bv[1]);
#pragma unroll
    for (int i = 0; i < 4; i++) {
      acc[i][0] = __builtin_amdgcn_mfma_f32_16x16x32_bf16(af[i], b0, acc[i][0], 0, 0, 0);
      acc[i][1] = __builtin_amdgcn_mfma_f32_16x16x32_bf16(af[i], b1v, acc[i][1], 0, 0, 0);
    }
  };

  loadA(0);
  loadB(0, vb[0]);
  stageA(0);
  __syncthreads();
  for (int kk = 0; kk < KS_ALL; kk++) {
    const int cur = kk & 1;
    if (kk + 1 < KS_ALL) {
      loadA(kk + 1);
      loadB(kk + 1, vb[cur ^ 1]);
    }
    compute(cur, vb[cur]);
    if (kk + 1 < KS_ALL) stageA(cur ^ 1);
    __syncthreads();
  }

  // ---- epilogue stage 1: h = leakyrelu(acc + b1) -> bf16 in LDS ----
  {
    const float bias0 = b1[wave * 32 + lo];
    const float bias1 = b1[wave * 32 + 16 + lo];
    unsigned short* hs = sh.e.hs;
#pragma unroll
    for (int i = 0; i < 4; i++) {
#pragma unroll
      for (int j = 0; j < 2; j++) {
        const int n = wave * 32 + j * 16 + lo;
        const float bias = j ? bias1 : bias0;
#pragma unroll
        for (int r = 0; r < 4; r++) {
          float v = acc[i][j][r] + bias;
          v = v > 0.f ? v : 0.01f * v;
          const int m = i * 16 + quad * 4 + r;
          unsigned u = __builtin_bit_cast(unsigned, v);
          hs[m * HSTR + n] = (unsigned short)((u + 0x8000u) >> 16);
        }
      }
    }
  }
  __syncthreads();

  // ---- epilogue stage 2: out = W2 @ h + b2, activations, store Hd ----
  {
    f32x4 acc2[5];
#pragma unroll
    for (int nt = 0; nt < 5; nt++) acc2[nt] = (f32x4){0.f, 0.f, 0.f, 0.f};
    const unsigned short* hb = sh.e.hs + (wave * 16 + lo) * HSTR + quad * 8;
#pragma unroll
    for (int ks = 0; ks < 4; ks++) {
      bf16x8 af = *(const bf16x8*)(hb + ks * 32);
#pragma unroll
      for (int nt = 0; nt < 5; nt++) {
        bf16x8 bf = *(const bf16x8*)(W2f + (size_t)((ks * 5 + nt) * 64 + lane) * 8);
        acc2[nt] = __builtin_amdgcn_mfma_f32_16x16x32_bf16(af, bf, acc2[nt], 0, 0, 0);
      }
    }
    const int mrow = m0 + wave * 16 + quad * 4;
#pragma unroll
    for (int nt = 0; nt < 5; nt++) {
      const int o = nt * 16 + lo;
      if (o < 5 * A_NUM + C_NUM) {
        const float bz = b2[o];
        const int t5 = (o < 5 * A_NUM) ? (o % 5) : 5;
#pragma unroll
        for (int r = 0; r < 4; r++) {
          const int m = mrow + r;
          if (m < HW) {
            float v = acc2[nt][r] + bz;
            if (t5 == 0) v = 1.f / (1.f + expf(-v));
            else if (t5 == 1 || t5 == 2) v = 1.f / (1.f + expf(-v)) - 0.5f;
            Hd[((size_t)b * HW + m) * OSTR + o] = v;
          }
        }
      }
    }
  }
}

// ---- gather: pure row copy from activated Hd -------------------------------
__global__ __launch_bounds__(256) void gather2(
    const int* __restrict__ pos_idx, const int* __restrict__ neg_idx,
    const float* __restrict__ Hd, float* __restrict__ out) {
  const int bid = blockIdx.x;
  if (bid < M_IDX / 8) {            // 512 blocks: 8 pos indices each
    const int g = threadIdx.x >> 5; // 32 lanes per index
    const int l = threadIdx.x & 31;
    const int slot = bid * 8 + g;
    const int idx = pos_idx[slot];
    const int b = idx / P_NUM, r = idx - b * P_NUM;
    const int a = r / HW, hw = r - a * HW;
    const float* row = Hd + ((size_t)b * HW + hw) * OSTR;
    if (l == 0)       out[CONF_OFF + slot] = row[a * 5];
    else if (l < 5)   out[OFFS_OFF + slot * 4 + (l - 1)] = row[a * 5 + l];
    else if (l < 25)  out[CLS_OFF + slot * C_NUM + (l - 5)] = row[5 * A_NUM + (l - 5)];
  } else {                          // 16 blocks: 1 neg index per thread
    const int tt = (bid - M_IDX / 8) * 256 + threadIdx.x;
    if (tt < M_IDX) {
      const int idx = neg_idx[tt];
      const int b = idx / P_NUM, r = idx - b * P_NUM;
      const int a = r / HW, hw = r - a * HW;
      out[CONF_OFF + M_IDX + tt] = Hd[((size_t)b * HW + hw) * OSTR + a * 5];
    }
  }
}

extern "C" void kernel_launch(void* const* d_in, const int* in_sizes, int n_in,
                              void* d_out, int out_size, void* d_ws, size_t ws_size,
                              hipStream_t stream) {
  const float* features = (const float*)d_in[0];
  const float* gridc    = (const float*)d_in[1];
  const float* anc      = (const float*)d_in[2];
  const float* bboxes   = (const float*)d_in[3];
  const int*   pos_idx  = (const int*)d_in[4];
  const int*   neg_idx  = (const int*)d_in[5];
  const float* W1       = (const float*)d_in[6];
  const float* b1       = (const float*)d_in[7];
  const float* W2       = (const float*)d_in[8];
  const float* b2       = (const float*)d_in[9];
  float* out = (float*)d_out;

  // ws: W1f (327680 B) | W2f (20480 B) | Hd (B*HW*OSTR fp32 = 8 MB)
  uint4* W1f = (uint4*)d_ws;
  uint4* W2f = (uint4*)((char*)d_ws + 327680);
  float* Hd  = (float*)((char*)d_ws + 327680 + 20480);

  hipLaunchKernelGGL(prep_w, dim3(85), dim3(256), 0, stream, W1, W2, W1f, W2f);
  hipLaunchKernelGGL(fused_main, dim3(GEMM_BLKS + IOU_BLKS), dim3(256), 0, stream,
                     features, (const unsigned short*)W1f,
                     (const unsigned short*)W2f, b1, b2, Hd,
                     gridc, anc, bboxes, out + IOU_OFF);
  hipLaunchKernelGGL(gather2, dim3(M_IDX / 8 + 16), dim3(256), 0, stream,
                     pos_idx, neg_idx, Hd, out);
}

// Round 2
// 261.359 us; speedup vs baseline: 1.0877x; 1.0877x over previous
//
#include <hip/hip_runtime.h>
#include <cstdint>

#define A_NUM 9
#define C_NUM 20
#define B_SZ 32
#define HW 784            // 28*28
#define P_NUM (A_NUM*HW)  // 7056
#define NBOX 64
#define CIN 1280
#define HID 128
#define M_IDX 4096
#define KS_ALL 40         // 1280/32 k-steps
#define HSF 132           // epilogue h LDS row stride in floats (528 B, 8B-aligned)
#define OSTR 80           // Hd row stride in floats (65 used, pad to 80)
#define IOU_PB 64         // p-rows per iou block

// output layout (flat concat in return order)
#define CONF_OFF 0
#define OFFS_OFF (2*M_IDX)                 // 8192
#define CLS_OFF  (OFFS_OFF + 4*M_IDX)      // 24576
#define IOU_OFF  (CLS_OFF + C_NUM*M_IDX)   // 106496

// fused-kernel grid split: 1568 gemm waves (32 b x 49 m-frags) = 392 blocks
#define GEMM_BLKS 392
#define IOU_BX ((P_NUM + IOU_PB - 1)/IOU_PB)      // 111
#define IOU_BLKS (IOU_BX*B_SZ)                    // 3552

typedef short bf16x8 __attribute__((ext_vector_type(8)));
typedef float f32x4  __attribute__((ext_vector_type(4)));

// round-half-up fp32->bf16, packed pair into one dword
__device__ __forceinline__ unsigned pack_bf16(float lo, float hi) {
  unsigned a = __builtin_bit_cast(unsigned, lo);
  unsigned b = __builtin_bit_cast(unsigned, hi);
  return ((a + 0x8000u) >> 16) | ((b + 0x8000u) & 0xffff0000u);
}

// ---- weight prep: W1 and W2 fp32 -> bf16 MFMA B-fragment order -------------
// W1f layout: [ks(40)][ntile(8)][lane(64)][k8], lane=(quad,lo): n=ntile*16+lo,
// k = ks*32 + quad*8 + j.
// W2f layout: [ks(4)][ntile(5)][lane(64)][k8], n(=o)=ntile*16+lo (o>=65 -> 0).
__global__ __launch_bounds__(256) void prep_w(const float* __restrict__ W1,
                                              const float* __restrict__ W2,
                                              uint4* __restrict__ W1f,
                                              uint4* __restrict__ W2f) {
  int id = blockIdx.x * 256 + threadIdx.x;  // 85*256 = 21760 threads
  if (id < 20480) {
    int lane = id & 63;
    int ntile = (id >> 6) & 7;
    int ks = id >> 9;                       // 0..39
    int lo = lane & 15, quad = lane >> 4;
    int n = ntile * 16 + lo;
    int k0 = ks * 32 + quad * 8;
    const float* src = W1 + n * CIN + k0;
    float4 x = *(const float4*)src;
    float4 y = *(const float4*)(src + 4);
    uint4 p;
    p.x = pack_bf16(x.x, x.y);
    p.y = pack_bf16(x.z, x.w);
    p.z = pack_bf16(y.x, y.y);
    p.w = pack_bf16(y.z, y.w);
    W1f[id] = p;
  } else {
    int i2 = id - 20480;                    // 0..1279
    int lane = i2 & 63;
    int ntile = (i2 >> 6) % 5;
    int ks = i2 / 320;                      // 0..3
    int lo = lane & 15, quad = lane >> 4;
    int n = ntile * 16 + lo;
    int k0 = ks * 32 + quad * 8;
    uint4 p = (uint4){0, 0, 0, 0};
    if (n < 5 * A_NUM + C_NUM) {
      const float* src = W2 + n * HID + k0;
      float4 x = *(const float4*)src;
      float4 y = *(const float4*)(src + 4);
      p.x = pack_bf16(x.x, x.y);
      p.y = pack_bf16(x.z, x.w);
      p.z = pack_bf16(y.x, y.y);
      p.w = pack_bf16(y.z, y.w);
    }
    W2f[i2] = p;
  }
}

// ---- fused: barrier-free per-wave GEMM + layer-2 head epilogue + IoU -------
union SharedU {
  float hs[4][16 * HSF];                                 // 33792 B (epilogue)
  struct { float sb[NBOX * 5]; float4 sp4[IOU_PB]; } i;  // 2304 B (iou)
};

__global__ __launch_bounds__(256) void fused_main(
    const float* __restrict__ F, const uint4* __restrict__ W1f,
    const uint4* __restrict__ W2f, const float* __restrict__ b1,
    const float* __restrict__ b2, float* __restrict__ Hd,
    const float* __restrict__ gridc, const float* __restrict__ anc,
    const float* __restrict__ bboxes, float* __restrict__ iou_out) {
  __shared__ SharedU sh;
  const int bid = blockIdx.x;
  const int t = threadIdx.x;

  if (bid >= GEMM_BLKS) {
    // ================= IoU part (unchanged math) =================
    const int bid2 = bid - GEMM_BLKS;
    const int b = bid2 / IOU_BX;
    const int p0 = (bid2 - b * IOU_BX) * IOU_PB;
    float* sb = sh.i.sb;
    float4* sp4 = sh.i.sp4;
    for (int i = t; i < NBOX * 5; i += 256) sb[i] = bboxes[b * NBOX * 5 + i];
    if (t < IOU_PB) {
      int p = p0 + t;
      float x1 = 0.f, y1 = 0.f, x2 = 0.f, y2 = 0.f;
      if (p < P_NUM) {
        int a = p / HW, hw = p - a * HW;
        float2 c = ((const float2*)gridc)[b * HW + hw];
        float hx = anc[a * 2 + 0] * 0.5f, hy = anc[a * 2 + 1] * 0.5f;
        x1 = c.x - hx; y1 = c.y - hy; x2 = c.x + hx; y2 = c.y + hy;
      }
      sp4[t] = make_float4(x1, y1, x2, y2);
    }
    __syncthreads();
    const int nl = (t & 15) * 4;
    const int pi = t >> 4;
#pragma unroll
    for (int ip = 0; ip < 4; ip++) {
      const int pl = pi + 16 * ip;
      const int p = p0 + pl;
      const float4 pb = sp4[pl];
      const float spA = (pb.z - pb.x) * (pb.w - pb.y);
      float4 res;
#pragma unroll
      for (int jn = 0; jn < 4; jn++) {
        const int n = nl + jn;
        float bx1 = sb[n * 5 + 0], by1 = sb[n * 5 + 1];
        float bx2 = sb[n * 5 + 2], by2 = sb[n * 5 + 3];
        float s_b = (bx2 - bx1) * (by2 - by1);
        float ix1 = fmaxf(pb.x, bx1), iy1 = fmaxf(pb.y, by1);
        float ix2 = fminf(pb.z, bx2), iy2 = fminf(pb.w, by2);
        float si = fmaxf(ix2 - ix1, 0.f) * fmaxf(iy2 - iy1, 0.f);
        float su = spA + s_b - si;
        float iou = fmaxf(si / (su + 1e-8f), 0.f);
        bool invalid = (su <= 0.f) | (spA <= 0.f) | (s_b <= 0.f) | (bx1 < 0.f);
        float v = invalid ? 0.f : iou;
        if (jn == 0) res.x = v; else if (jn == 1) res.y = v;
        else if (jn == 2) res.z = v; else res.w = v;
      }
      if (p < P_NUM)
        *(float4*)&iou_out[((size_t)(b * P_NUM + p)) * 64 + nl] = res;
    }
    return;
  }

  // ======== GEMM: one wave owns 16m x 128n, full K=1280, no barriers ========
  const int w = t >> 6, lane = t & 63;
  const int quad = lane >> 4, lo = lane & 15;
  const int g = bid * 4 + w;        // 0..1567 global wave id
  const int b = g / 49;
  const int mf = g - b * 49;
  const int m0 = mf * 16;

  // A-frag element addr: F[b][k][m0+lo], k = kk*32 + quad*8 + j
  const float* Fq = F + (size_t)b * CIN * HW + (size_t)quad * 8 * HW + m0 + lo;

  f32x4 acc[8];
#pragma unroll
  for (int i = 0; i < 8; i++) acc[i] = (f32x4){0.f, 0.f, 0.f, 0.f};

  float va0[8], va1[8];
  uint4 vb0[8], vb1[8];

  auto loadA = [&](int kk, float* va) {
    const float* p = Fq + (size_t)kk * 32 * HW;
#pragma unroll
    for (int j = 0; j < 8; j++) va[j] = p[(size_t)j * HW];
  };
  auto loadB = [&](int kk, uint4* vb) {
    const uint4* p = W1f + (size_t)kk * 512 + lane;
#pragma unroll
    for (int nf = 0; nf < 8; nf++) vb[nf] = p[nf * 64];
  };
  auto step = [&](const float* va, const uint4* vb) {
    uint4 ap;
    ap.x = pack_bf16(va[0], va[1]);
    ap.y = pack_bf16(va[2], va[3]);
    ap.z = pack_bf16(va[4], va[5]);
    ap.w = pack_bf16(va[6], va[7]);
    bf16x8 af = __builtin_bit_cast(bf16x8, ap);
#pragma unroll
    for (int nf = 0; nf < 8; nf++)
      acc[nf] = __builtin_amdgcn_mfma_f32_16x16x32_bf16(
          af, __builtin_bit_cast(bf16x8, vb[nf]), acc[nf], 0, 0, 0);
  };

  loadA(0, va0); loadB(0, vb0);
  loadA(1, va1); loadB(1, vb1);
#pragma unroll 2
  for (int kk = 0; kk < KS_ALL; kk += 2) {
    step(va0, vb0);
    if (kk + 2 < KS_ALL) { loadA(kk + 2, va0); loadB(kk + 2, vb0); }
    step(va1, vb1);
    if (kk + 3 < KS_ALL) { loadA(kk + 3, va1); loadB(kk + 3, vb1); }
  }

  // ---- epilogue stage 1: h = leakyrelu(acc + b1) -> fp32 LDS (per-wave) ----
  {
    float* hsw = sh.hs[w];
#pragma unroll
    for (int nf = 0; nf < 8; nf++) {
      const float bb = b1[nf * 16 + lo];
#pragma unroll
      for (int r = 0; r < 4; r++) {
        float v = acc[nf][r] + bb;
        v = v > 0.f ? v : 0.01f * v;
        hsw[(quad * 4 + r) * HSF + nf * 16 + lo] = v;
      }
    }
  }
  __syncthreads();

  // ---- epilogue stage 2: out = W2 @ h + b2, activations, store Hd ----------
  {
    f32x4 acc2[5];
#pragma unroll
    for (int nt = 0; nt < 5; nt++) acc2[nt] = (f32x4){0.f, 0.f, 0.f, 0.f};
    const float* hrow = sh.hs[w] + lo * HSF + quad * 8;
#pragma unroll
    for (int ks = 0; ks < 4; ks++) {
      const float* hp = hrow + ks * 32;
      float2 p0 = *(const float2*)(hp + 0);
      float2 p1 = *(const float2*)(hp + 2);
      float2 p2 = *(const float2*)(hp + 4);
      float2 p3 = *(const float2*)(hp + 6);
      uint4 ap;
      ap.x = pack_bf16(p0.x, p0.y);
      ap.y = pack_bf16(p1.x, p1.y);
      ap.z = pack_bf16(p2.x, p2.y);
      ap.w = pack_bf16(p3.x, p3.y);
      bf16x8 af = __builtin_bit_cast(bf16x8, ap);
#pragma unroll
      for (int nt = 0; nt < 5; nt++) {
        bf16x8 bf = __builtin_bit_cast(bf16x8, W2f[(ks * 5 + nt) * 64 + lane]);
        acc2[nt] = __builtin_amdgcn_mfma_f32_16x16x32_bf16(af, bf, acc2[nt], 0, 0, 0);
      }
    }
    const int mrow = m0 + quad * 4;
#pragma unroll
    for (int nt = 0; nt < 5; nt++) {
      const int o = nt * 16 + lo;
      if (o < 5 * A_NUM + C_NUM) {
        const float bz = b2[o];
        const int t5 = (o < 5 * A_NUM) ? (o % 5) : 5;
#pragma unroll
        for (int r = 0; r < 4; r++) {
          const int m = mrow + r;
          float v = acc2[nt][r] + bz;
          if (t5 == 0) v = 1.f / (1.f + expf(-v));
          else if (t5 == 1 || t5 == 2) v = 1.f / (1.f + expf(-v)) - 0.5f;
          Hd[((size_t)b * HW + m) * OSTR + o] = v;
        }
      }
    }
  }
}

// ---- gather: pure row copy from activated Hd -------------------------------
__global__ __launch_bounds__(256) void gather2(
    const int* __restrict__ pos_idx, const int* __restrict__ neg_idx,
    const float* __restrict__ Hd, float* __restrict__ out) {
  const int bid = blockIdx.x;
  if (bid < M_IDX / 8) {            // 512 blocks: 8 pos indices each
    const int g = threadIdx.x >> 5; // 32 lanes per index
    const int l = threadIdx.x & 31;
    const int slot = bid * 8 + g;
    const int idx = pos_idx[slot];
    const int b = idx / P_NUM, r = idx - b * P_NUM;
    const int a = r / HW, hw = r - a * HW;
    const float* row = Hd + ((size_t)b * HW + hw) * OSTR;
    if (l == 0)       out[CONF_OFF + slot] = row[a * 5];
    else if (l < 5)   out[OFFS_OFF + slot * 4 + (l - 1)] = row[a * 5 + l];
    else if (l < 25)  out[CLS_OFF + slot * C_NUM + (l - 5)] = row[5 * A_NUM + (l - 5)];
  } else {                          // 16 blocks: 1 neg index per thread
    const int tt = (bid - M_IDX / 8) * 256 + threadIdx.x;
    if (tt < M_IDX) {
      const int idx = neg_idx[tt];
      const int b = idx / P_NUM, r = idx - b * P_NUM;
      const int a = r / HW, hw = r - a * HW;
      out[CONF_OFF + M_IDX + tt] = Hd[((size_t)b * HW + hw) * OSTR + a * 5];
    }
  }
}

extern "C" void kernel_launch(void* const* d_in, const int* in_sizes, int n_in,
                              void* d_out, int out_size, void* d_ws, size_t ws_size,
                              hipStream_t stream) {
  const float* features = (const float*)d_in[0];
  const float* gridc    = (const float*)d_in[1];
  const float* anc      = (const float*)d_in[2];
  const float* bboxes   = (const float*)d_in[3];
  const int*   pos_idx  = (const int*)d_in[4];
  const int*   neg_idx  = (const int*)d_in[5];
  const float* W1       = (const float*)d_in[6];
  const float* b1       = (const float*)d_in[7];
  const float* W2       = (const float*)d_in[8];
  const float* b2       = (const float*)d_in[9];
  float* out = (float*)d_out;

  // ws: W1f (327680 B) | W2f (20480 B) | Hd (B*HW*OSTR fp32 = 8 MB)
  uint4* W1f = (uint4*)d_ws;
  uint4* W2f = (uint4*)((char*)d_ws + 327680);
  float* Hd  = (float*)((char*)d_ws + 327680 + 20480);

  hipLaunchKernelGGL(prep_w, dim3(85), dim3(256), 0, stream, W1, W2, W1f, W2f);
  hipLaunchKernelGGL(fused_main, dim3(GEMM_BLKS + IOU_BLKS), dim3(256), 0, stream,
                     features, W1f, W2f, b1, b2, Hd,
                     gridc, anc, bboxes, out + IOU_OFF);
  hipLaunchKernelGGL(gather2, dim3(M_IDX / 8 + 16), dim3(256), 0, stream,
                     pos_idx, neg_idx, Hd, out);
}

// Round 4
// 255.834 us; speedup vs baseline: 1.1112x; 1.0216x over previous
//
#include <hip/hip_runtime.h>
#include <cstdint>

#define A_NUM 9
#define C_NUM 20
#define B_SZ 32
#define HW 784            // 28*28
#define P_NUM (A_NUM*HW)  // 7056
#define NBOX 64
#define CIN 1280
#define HID 128
#define M_IDX 4096
#define KS_W 10           // k-steps per wave (K-split 4: 4*10*32 = 1280)
#define HSTR2 136         // h LDS row stride in bf16 elems (272 B, 16B-aligned)
#define OSTR 80           // Hd row stride in floats (65 used, pad to 80)
#define IOU_PB 64         // p-rows per iou block

// output layout (flat concat in return order)
#define CONF_OFF 0
#define OFFS_OFF (2*M_IDX)                 // 8192
#define CLS_OFF  (OFFS_OFF + 4*M_IDX)      // 24576
#define IOU_OFF  (CLS_OFF + C_NUM*M_IDX)   // 106496

// fused-kernel grid split: one block per 16-row tile (32 b x 49 mf)
#define GEMM_BLKS (B_SZ*49)                       // 1568
#define IOU_BX ((P_NUM + IOU_PB - 1)/IOU_PB)      // 111
#define IOU_BLKS (IOU_BX*B_SZ)                    // 3552

typedef short bf16x8 __attribute__((ext_vector_type(8)));
typedef float f32x4  __attribute__((ext_vector_type(4)));

// round-half-up fp32->bf16, packed pair into one dword
__device__ __forceinline__ unsigned pack_bf16(float lo, float hi) {
  unsigned a = __builtin_bit_cast(unsigned, lo);
  unsigned b = __builtin_bit_cast(unsigned, hi);
  return ((a + 0x8000u) >> 16) | ((b + 0x8000u) & 0xffff0000u);
}

// ---- weight prep: W1 and W2 fp32 -> bf16 MFMA B-fragment order -------------
// W1f layout: [ks(40)][ntile(8)][lane(64)][k8], lane=(quad,lo): n=ntile*16+lo,
// k = ks*32 + quad*8 + j.
// W2f layout: [ks(4)][ntile(5)][lane(64)][k8], n(=o)=ntile*16+lo (o>=65 -> 0).
__global__ __launch_bounds__(256) void prep_w(const float* __restrict__ W1,
                                              const float* __restrict__ W2,
                                              uint4* __restrict__ W1f,
                                              uint4* __restrict__ W2f) {
  int id = blockIdx.x * 256 + threadIdx.x;  // 85*256 = 21760 threads
  if (id < 20480) {
    int lane = id & 63;
    int ntile = (id >> 6) & 7;
    int ks = id >> 9;                       // 0..39
    int lo = lane & 15, quad = lane >> 4;
    int n = ntile * 16 + lo;
    int k0 = ks * 32 + quad * 8;
    const float* src = W1 + n * CIN + k0;
    float4 x = *(const float4*)src;
    float4 y = *(const float4*)(src + 4);
    uint4 p;
    p.x = pack_bf16(x.x, x.y);
    p.y = pack_bf16(x.z, x.w);
    p.z = pack_bf16(y.x, y.y);
    p.w = pack_bf16(y.z, y.w);
    W1f[id] = p;
  } else {
    int i2 = id - 20480;                    // 0..1279
    int lane = i2 & 63;
    int ntile = (i2 >> 6) % 5;
    int ks = i2 / 320;                      // 0..3
    int lo = lane & 15, quad = lane >> 4;
    int n = ntile * 16 + lo;
    int k0 = ks * 32 + quad * 8;
    uint4 p = (uint4){0, 0, 0, 0};
    if (n < 5 * A_NUM + C_NUM) {
      const float* src = W2 + n * HID + k0;
      float4 x = *(const float4*)src;
      float4 y = *(const float4*)(src + 4);
      p.x = pack_bf16(x.x, x.y);
      p.y = pack_bf16(x.z, x.w);
      p.z = pack_bf16(y.x, y.y);
      p.w = pack_bf16(y.z, y.w);
    }
    W2f[i2] = p;
  }
}

// ---- fused: K-split-in-block GEMM + LDS reduce + W2 head + IoU -------------
// (audited r3: uniform barriers, all indices in bounds, LDS 37120 B, 16B-aligned)
union SharedU {
  struct {
    f32x4 red[4][8][64];                 // 32768 B: per-wave partial acc
    unsigned short h[16 * HSTR2];        //  4352 B: bf16 h tile [16][128]
  } g;
  struct { float sb[NBOX * 5]; float4 sp4[IOU_PB]; } i;  // 2304 B (iou)
};

__global__ __launch_bounds__(256) void fused_main(
    const float* __restrict__ F, const uint4* __restrict__ W1f,
    const uint4* __restrict__ W2f, const float* __restrict__ b1,
    const float* __restrict__ b2, float* __restrict__ Hd,
    const float* __restrict__ gridc, const float* __restrict__ anc,
    const float* __restrict__ bboxes, float* __restrict__ iou_out) {
  __shared__ SharedU sh;
  const int bid = blockIdx.x;
  const int t = threadIdx.x;

  if (bid >= GEMM_BLKS) {
    // ================= IoU part (unchanged math) =================
    const int bid2 = bid - GEMM_BLKS;
    const int b = bid2 / IOU_BX;
    const int p0 = (bid2 - b * IOU_BX) * IOU_PB;
    float* sb = sh.i.sb;
    float4* sp4 = sh.i.sp4;
    for (int i = t; i < NBOX * 5; i += 256) sb[i] = bboxes[b * NBOX * 5 + i];
    if (t < IOU_PB) {
      int p = p0 + t;
      float x1 = 0.f, y1 = 0.f, x2 = 0.f, y2 = 0.f;
      if (p < P_NUM) {
        int a = p / HW, hw = p - a * HW;
        float2 c = ((const float2*)gridc)[b * HW + hw];
        float hx = anc[a * 2 + 0] * 0.5f, hy = anc[a * 2 + 1] * 0.5f;
        x1 = c.x - hx; y1 = c.y - hy; x2 = c.x + hx; y2 = c.y + hy;
      }
      sp4[t] = make_float4(x1, y1, x2, y2);
    }
    __syncthreads();
    const int nl = (t & 15) * 4;
    const int pi = t >> 4;
#pragma unroll
    for (int ip = 0; ip < 4; ip++) {
      const int pl = pi + 16 * ip;
      const int p = p0 + pl;
      const float4 pb = sp4[pl];
      const float spA = (pb.z - pb.x) * (pb.w - pb.y);
      float4 res;
#pragma unroll
      for (int jn = 0; jn < 4; jn++) {
        const int n = nl + jn;
        float bx1 = sb[n * 5 + 0], by1 = sb[n * 5 + 1];
        float bx2 = sb[n * 5 + 2], by2 = sb[n * 5 + 3];
        float s_b = (bx2 - bx1) * (by2 - by1);
        float ix1 = fmaxf(pb.x, bx1), iy1 = fmaxf(pb.y, by1);
        float ix2 = fminf(pb.z, bx2), iy2 = fminf(pb.w, by2);
        float si = fmaxf(ix2 - ix1, 0.f) * fmaxf(iy2 - iy1, 0.f);
        float su = spA + s_b - si;
        float iou = fmaxf(si / (su + 1e-8f), 0.f);
        bool invalid = (su <= 0.f) | (spA <= 0.f) | (s_b <= 0.f) | (bx1 < 0.f);
        float v = invalid ? 0.f : iou;
        if (jn == 0) res.x = v; else if (jn == 1) res.y = v;
        else if (jn == 2) res.z = v; else res.w = v;
      }
      if (p < P_NUM)
        *(float4*)&iou_out[((size_t)(b * P_NUM + p)) * 64 + nl] = res;
    }
    return;
  }

  // ===== GEMM: block owns 16m x 128n tile; wave w sums k in [320w,320w+320) =
  const int w = t >> 6, lane = t & 63;
  const int quad = lane >> 4, lo = lane & 15;
  const int b = bid / 49;
  const int mf = bid - b * 49;
  const int m0 = mf * 16;

  // A-frag element addr: F[b][k][m0+lo], k = w*320 + kk*32 + quad*8 + j
  const float* Fq = F + (size_t)b * CIN * HW +
                    (size_t)(w * (KS_W * 32) + quad * 8) * HW + m0 + lo;
  const uint4* Wq = W1f + (size_t)(w * KS_W) * 512 + lane;

  f32x4 acc[8];
#pragma unroll
  for (int i = 0; i < 8; i++) acc[i] = (f32x4){0.f, 0.f, 0.f, 0.f};

  float va0[8], va1[8];
  uint4 vb0[8], vb1[8];

  auto loadA = [&](int kk, float* va) {
    const float* p = Fq + (size_t)kk * 32 * HW;
#pragma unroll
    for (int j = 0; j < 8; j++) va[j] = p[(size_t)j * HW];
  };
  auto loadB = [&](int kk, uint4* vb) {
    const uint4* p = Wq + (size_t)kk * 512;
#pragma unroll
    for (int nf = 0; nf < 8; nf++) vb[nf] = p[nf * 64];
  };
  auto step = [&](const float* va, const uint4* vb) {
    uint4 ap;
    ap.x = pack_bf16(va[0], va[1]);
    ap.y = pack_bf16(va[2], va[3]);
    ap.z = pack_bf16(va[4], va[5]);
    ap.w = pack_bf16(va[6], va[7]);
    bf16x8 af = __builtin_bit_cast(bf16x8, ap);
#pragma unroll
    for (int nf = 0; nf < 8; nf++)
      acc[nf] = __builtin_amdgcn_mfma_f32_16x16x32_bf16(
          af, __builtin_bit_cast(bf16x8, vb[nf]), acc[nf], 0, 0, 0);
  };

  loadA(0, va0); loadB(0, vb0);
  loadA(1, va1); loadB(1, vb1);
#pragma unroll 2
  for (int kk = 0; kk < KS_W; kk += 2) {
    step(va0, vb0);
    if (kk + 2 < KS_W) { loadA(kk + 2, va0); loadB(kk + 2, vb0); }
    step(va1, vb1);
    if (kk + 3 < KS_W) { loadA(kk + 3, va1); loadB(kk + 3, vb1); }
  }

  // ---- K-split reduce: stash partials, one barrier, sum 4-way --------------
#pragma unroll
  for (int nf = 0; nf < 8; nf++) sh.g.red[w][nf][lane] = acc[nf];
  __syncthreads();

  // wave w owns nf in {2w, 2w+1}: sum partials, bias, leaky, bf16 -> h tile
#pragma unroll
  for (int i = 0; i < 2; i++) {
    const int nf = 2 * w + i;
    f32x4 s = sh.g.red[0][nf][lane];
    s += sh.g.red[1][nf][lane];
    s += sh.g.red[2][nf][lane];
    s += sh.g.red[3][nf][lane];
    const float bb = b1[nf * 16 + lo];
#pragma unroll
    for (int r = 0; r < 4; r++) {
      float v = s[r] + bb;
      v = v > 0.f ? v : 0.01f * v;
      unsigned u = __builtin_bit_cast(unsigned, v);
      sh.g.h[(quad * 4 + r) * HSTR2 + nf * 16 + lo] =
          (unsigned short)((u + 0x8000u) >> 16);
    }
  }
  __syncthreads();

  // ---- W2 head: wave w computes nt = w (wave 0 also nt = 4) ----------------
  {
    bf16x8 af[4];
#pragma unroll
    for (int ks = 0; ks < 4; ks++)
      af[ks] = *(const bf16x8*)(sh.g.h + lo * HSTR2 + ks * 32 + quad * 8);
    const int mrow = m0 + quad * 4;
#pragma unroll
    for (int rep = 0; rep < 2; rep++) {
      const int nt = rep ? 4 : w;
      if (rep && w != 0) break;
      f32x4 acc2 = (f32x4){0.f, 0.f, 0.f, 0.f};
#pragma unroll
      for (int ks = 0; ks < 4; ks++) {
        bf16x8 bf = __builtin_bit_cast(bf16x8, W2f[(ks * 5 + nt) * 64 + lane]);
        acc2 = __builtin_amdgcn_mfma_f32_16x16x32_bf16(af[ks], bf, acc2, 0, 0, 0);
      }
      const int o = nt * 16 + lo;
      if (o < 5 * A_NUM + C_NUM) {
        const float bz = b2[o];
        const int t5 = (o < 5 * A_NUM) ? (o % 5) : 5;
#pragma unroll
        for (int r = 0; r < 4; r++) {
          const int m = mrow + r;
          float v = acc2[r] + bz;
          if (t5 == 0) v = 1.f / (1.f + expf(-v));
          else if (t5 == 1 || t5 == 2) v = 1.f / (1.f + expf(-v)) - 0.5f;
          Hd[((size_t)b * HW + m) * OSTR + o] = v;
        }
      }
    }
  }
}

// ---- gather: pure row copy from activated Hd -------------------------------
__global__ __launch_bounds__(256) void gather2(
    const int* __restrict__ pos_idx, const int* __restrict__ neg_idx,
    const float* __restrict__ Hd, float* __restrict__ out) {
  const int bid = blockIdx.x;
  if (bid < M_IDX / 8) {            // 512 blocks: 8 pos indices each
    const int g = threadIdx.x >> 5; // 32 lanes per index
    const int l = threadIdx.x & 31;
    const int slot = bid * 8 + g;
    const int idx = pos_idx[slot];
    const int b = idx / P_NUM, r = idx - b * P_NUM;
    const int a = r / HW, hw = r - a * HW;
    const float* row = Hd + ((size_t)b * HW + hw) * OSTR;
    if (l == 0)       out[CONF_OFF + slot] = row[a * 5];
    else if (l < 5)   out[OFFS_OFF + slot * 4 + (l - 1)] = row[a * 5 + l];
    else if (l < 25)  out[CLS_OFF + slot * C_NUM + (l - 5)] = row[5 * A_NUM + (l - 5)];
  } else {                          // 16 blocks: 1 neg index per thread
    const int tt = (bid - M_IDX / 8) * 256 + threadIdx.x;
    if (tt < M_IDX) {
      const int idx = neg_idx[tt];
      const int b = idx / P_NUM, r = idx - b * P_NUM;
      const int a = r / HW, hw = r - a * HW;
      out[CONF_OFF + M_IDX + tt] = Hd[((size_t)b * HW + hw) * OSTR + a * 5];
    }
  }
}

extern "C" void kernel_launch(void* const* d_in, const int* in_sizes, int n_in,
                              void* d_out, int out_size, void* d_ws, size_t ws_size,
                              hipStream_t stream) {
  const float* features = (const float*)d_in[0];
  const float* gridc    = (const float*)d_in[1];
  const float* anc      = (const float*)d_in[2];
  const float* bboxes   = (const float*)d_in[3];
  const int*   pos_idx  = (const int*)d_in[4];
  const int*   neg_idx  = (const int*)d_in[5];
  const float* W1       = (const float*)d_in[6];
  const float* b1       = (const float*)d_in[7];
  const float* W2       = (const float*)d_in[8];
  const float* b2       = (const float*)d_in[9];
  float* out = (float*)d_out;

  // ws: W1f (327680 B) | W2f (20480 B) | Hd (B*HW*OSTR fp32 = 8 MB)
  uint4* W1f = (uint4*)d_ws;
  uint4* W2f = (uint4*)((char*)d_ws + 327680);
  float* Hd  = (float*)((char*)d_ws + 327680 + 20480);

  hipLaunchKernelGGL(prep_w, dim3(85), dim3(256), 0, stream, W1, W2, W1f, W2f);
  hipLaunchKernelGGL(fused_main, dim3(GEMM_BLKS + IOU_BLKS), dim3(256), 0, stream,
                     features, W1f, W2f, b1, b2, Hd,
                     gridc, anc, bboxes, out + IOU_OFF);
  hipLaunchKernelGGL(gather2, dim3(M_IDX / 8 + 16), dim3(256), 0, stream,
                     pos_idx, neg_idx, Hd, out);
}